// Round 1
// baseline (2877.547 us; speedup 1.0000x reference)
//
#include <hip/hip_runtime.h>

#define D 128

// ---------------- degree count: deg[dst]++ ----------------
__global__ __launch_bounds__(256) void deg_kernel(const int* __restrict__ dst,
                                                  int* __restrict__ deg, int E) {
    int tid = blockIdx.x * 256 + threadIdx.x;
    if (tid < E) atomicAdd(&deg[dst[tid]], 1);
}

// ---------------- dinv = rsqrt(deg + 1 self-loop) ----------------
__global__ __launch_bounds__(256) void dinv_kernel(const int* __restrict__ deg,
                                                   float* __restrict__ dinv, int N) {
    int i = blockIdx.x * 256 + threadIdx.x;
    if (i < N) dinv[i] = rsqrtf((float)deg[i] + 1.0f);
}

// ---------------- scatter: agg[dst] += x[src] * dinv[src]*dinv[dst] ----------
// 32 threads per edge, one float4 (4 elems) per thread.
__global__ __launch_bounds__(256) void scatter_kernel(const float* __restrict__ x,
                                                      const int* __restrict__ src,
                                                      const int* __restrict__ dst,
                                                      const float* __restrict__ dinv,
                                                      float* __restrict__ agg, int E) {
    long long tid = (long long)blockIdx.x * 256 + threadIdx.x;
    int e = (int)(tid >> 5);
    if (e >= E) return;
    int c = (int)(tid & 31);
    int s = src[e];
    int d = dst[e];
    float norm = dinv[s] * dinv[d];
    float4 v = ((const float4*)x)[(size_t)s * 32 + c];
    float* ap = agg + (size_t)d * D + c * 4;
    atomicAdd(ap + 0, v.x * norm);
    atomicAdd(ap + 1, v.y * norm);
    atomicAdd(ap + 2, v.z * norm);
    atomicAdd(ap + 3, v.w * norm);
}

// ---------------- fused: out = x + relu((agg + x*dinv^2) @ W^T + b) ----------
// Block = 256 threads (4 waves), 16 rows per block (4 rows per wave).
// W (128x128 fp32, 64KB) staged in LDS with row stride 132 dwords:
// lane l reads dwords [132*l + 4c .. +3]; bank hits are uniform (8 dwords/bank)
// so ds_read_b128 runs at the conflict-free floor.
__global__ __launch_bounds__(256) void final_kernel(const float* __restrict__ agg,
                                                    const float* __restrict__ x,
                                                    const float* __restrict__ dinv,
                                                    const float* __restrict__ W,
                                                    const float* __restrict__ bias,
                                                    float* __restrict__ out, int N) {
    __shared__ float Wl[128 * 132];     // 67.6 KB
    __shared__ float rowbuf[16 * 128];  // 8 KB   (total ~75.7KB -> 2 blocks/CU of 160KB)
    const int lane = threadIdx.x & 63;
    const int wave = threadIdx.x >> 6;

    // stage W: idx = j*32 + c (float4 granularity), coalesced global read
    for (int idx = threadIdx.x; idx < 128 * 32; idx += 256) {
        int j = idx >> 5, c = idx & 31;
        float4 w = ((const float4*)W)[idx];
        *(float4*)&Wl[j * 132 + c * 4] = w;
    }

    // stage 16 rows: row[k] = agg[i][k] + x[i][k]*dinv[i]^2  (self-loop folded in)
    int base = blockIdx.x * 16;
    int trow = threadIdx.x >> 4;  // 0..15
    int tc = threadIdx.x & 15;    // float4 index 0..15 (and +16)
    int grow = base + trow;
    if (grow < N) {
        float dv = dinv[grow];
        float d2 = dv * dv;
        size_t off = (size_t)grow * D;
        const float4* a4 = (const float4*)(agg + off);
        const float4* x4 = (const float4*)(x + off);
        float4 a0 = a4[tc], x0 = x4[tc];
        float4 a1 = a4[tc + 16], x1 = x4[tc + 16];
        float4 r0 = make_float4(a0.x + x0.x * d2, a0.y + x0.y * d2,
                                a0.z + x0.z * d2, a0.w + x0.w * d2);
        float4 r1 = make_float4(a1.x + x1.x * d2, a1.y + x1.y * d2,
                                a1.z + x1.z * d2, a1.w + x1.w * d2);
        *(float4*)&rowbuf[trow * D + tc * 4] = r0;
        *(float4*)&rowbuf[trow * D + (tc + 16) * 4] = r1;
    }
    __syncthreads();

    // each wave: 4 rows, each lane: output cols j0=lane, j1=lane+64
    const int j0 = lane, j1 = lane + 64;
    float acc0[4] = {0.f, 0.f, 0.f, 0.f};
    float acc1[4] = {0.f, 0.f, 0.f, 0.f};
    const float* w0p = &Wl[j0 * 132];
    const float* w1p = &Wl[j1 * 132];
    const float* rp = &rowbuf[wave * 4 * D];
#pragma unroll 4
    for (int c = 0; c < 32; ++c) {
        float4 w0 = *(const float4*)(w0p + c * 4);
        float4 w1 = *(const float4*)(w1p + c * 4);
#pragma unroll
        for (int r = 0; r < 4; ++r) {
            float4 rv = *(const float4*)(rp + r * D + c * 4);
            acc0[r] += rv.x * w0.x + rv.y * w0.y + rv.z * w0.z + rv.w * w0.w;
            acc1[r] += rv.x * w1.x + rv.y * w1.y + rv.z * w1.z + rv.w * w1.w;
        }
    }

    float b0 = bias[j0], b1 = bias[j1];
#pragma unroll
    for (int r = 0; r < 4; ++r) {
        int row = base + wave * 4 + r;
        if (row < N) {
            size_t off = (size_t)row * D;
            float h0 = acc0[r] + b0;
            float h1 = acc1[r] + b1;
            out[off + j0] = x[off + j0] + (h0 > 0.f ? h0 : 0.f);
            out[off + j1] = x[off + j1] + (h1 > 0.f ? h1 : 0.f);
        }
    }
}

extern "C" void kernel_launch(void* const* d_in, const int* in_sizes, int n_in,
                              void* d_out, int out_size, void* d_ws, size_t ws_size,
                              hipStream_t stream) {
    const float* x = (const float*)d_in[0];
    const int* ei = (const int*)d_in[1];
    const float* W = (const float*)d_in[2];
    const float* bias = (const float*)d_in[3];
    float* out = (float*)d_out;

    const int N = in_sizes[0] / D;   // 50000
    const int E = in_sizes[1] / 2;   // 1,600,000
    const int* src = ei;
    const int* dst = ei + E;

    // workspace layout: [agg: N*D floats][deg: N ints][dinv: N floats]
    float* agg = (float*)d_ws;
    int* deg = (int*)((char*)d_ws + (size_t)N * D * sizeof(float));
    float* dinv = (float*)((char*)deg + (size_t)N * sizeof(int));

    // zero agg + deg in one shot (they are contiguous)
    hipMemsetAsync(d_ws, 0, (size_t)N * D * sizeof(float) + (size_t)N * sizeof(int), stream);

    deg_kernel<<<(E + 255) / 256, 256, 0, stream>>>(dst, deg, E);
    dinv_kernel<<<(N + 255) / 256, 256, 0, stream>>>(deg, dinv, N);

    long long sc_threads = (long long)E * 32;
    int sc_blocks = (int)((sc_threads + 255) / 256);
    scatter_kernel<<<sc_blocks, 256, 0, stream>>>(x, src, dst, dinv, agg, E);

    int fin_blocks = (N + 15) / 16;
    final_kernel<<<fin_blocks, 256, 0, stream>>>(agg, x, dinv, W, bias, out, N);
}

// Round 2
// 463.959 us; speedup vs baseline: 6.2022x; 6.2022x over previous
//
#include <hip/hip_runtime.h>

#define D 128
#define SCAN_B 256

// ---------------- degree count: deg[dst]++ (in-edges only) ----------------
__global__ __launch_bounds__(256) void deg_kernel(const int* __restrict__ dst,
                                                  int* __restrict__ deg, int E) {
    int tid = blockIdx.x * 256 + threadIdx.x;
    if (tid < E) atomicAdd(&deg[dst[tid]], 1);
}

// ---------------- dinv = rsqrt(deg + 1 self-loop) ----------------
__global__ __launch_bounds__(256) void dinv_kernel(const int* __restrict__ deg,
                                                   float* __restrict__ dinv, int N) {
    int i = blockIdx.x * 256 + threadIdx.x;
    if (i < N) dinv[i] = rsqrtf((float)deg[i] + 1.0f);
}

// ---------------- scan step 1: per-block partial sums of deg ----------------
__global__ __launch_bounds__(SCAN_B) void scan_reduce(const int* __restrict__ deg,
                                                      int* __restrict__ partials, int N) {
    __shared__ int sh[SCAN_B];
    int t = threadIdx.x;
    int i = blockIdx.x * SCAN_B + t;
    sh[t] = (i < N) ? deg[i] : 0;
    __syncthreads();
    for (int off = SCAN_B / 2; off > 0; off >>= 1) {
        if (t < off) sh[t] += sh[t + off];
        __syncthreads();
    }
    if (t == 0) partials[blockIdx.x] = sh[0];
}

// ---------------- scan step 2: serial exclusive scan of partials ----------------
__global__ void scan_partials(int* __restrict__ partials, int nb) {
    if (threadIdx.x == 0 && blockIdx.x == 0) {
        int run = 0;
        for (int i = 0; i < nb; ++i) {
            int t = partials[i];
            partials[i] = run;
            run += t;
        }
    }
}

// ---------------- scan step 3: block-level exclusive scan + offset ----------------
__global__ __launch_bounds__(SCAN_B) void scan_apply(const int* __restrict__ deg,
                                                     const int* __restrict__ partials,
                                                     int* __restrict__ base, int N) {
    __shared__ int sh[SCAN_B];
    int t = threadIdx.x;
    int i = blockIdx.x * SCAN_B + t;
    int v = (i < N) ? deg[i] : 0;
    sh[t] = v;
    __syncthreads();
    // Hillis-Steele inclusive scan
    for (int off = 1; off < SCAN_B; off <<= 1) {
        int add = (t >= off) ? sh[t - off] : 0;
        __syncthreads();
        sh[t] += add;
        __syncthreads();
    }
    if (i < N) base[i] = partials[blockIdx.x] + sh[t] - v;  // exclusive
}

// ---------------- placement: counting-sort edges by dst ----------------
// After this kernel: base[d] = end offset of node d's segment (start = base[d-1]).
__global__ __launch_bounds__(256) void place_kernel(const int* __restrict__ src,
                                                    const int* __restrict__ dst,
                                                    int* __restrict__ base,
                                                    int* __restrict__ srcs, int E) {
    int e = blockIdx.x * 256 + threadIdx.x;
    if (e < E) {
        int d = dst[e];
        int p = atomicAdd(&base[d], 1);
        srcs[p] = src[e];
    }
}

// ---------------- gather: one wave per node, register accumulation ----------------
// lane l holds cols l and l+64. agg[d] = sum_e x[src_e]*dinv[src_e]*dinv[d] + x[d]*dinv[d]^2
__global__ __launch_bounds__(256) void gather_kernel(const float* __restrict__ x,
                                                     const int* __restrict__ srcs,
                                                     const int* __restrict__ base,
                                                     const float* __restrict__ dinv,
                                                     float* __restrict__ agg, int N) {
    int node = blockIdx.x * 4 + (threadIdx.x >> 6);
    if (node >= N) return;
    int lane = threadIdx.x & 63;
    int start = (node == 0) ? 0 : base[node - 1];
    int end = base[node];
    float dvd = dinv[node];
    size_t noff = (size_t)node * D;
    float acc0 = x[noff + lane] * dvd * dvd;         // self-loop
    float acc1 = x[noff + 64 + lane] * dvd * dvd;

    int e = start;
    // unroll by 2 for memory-level parallelism
    for (; e + 1 < end; e += 2) {
        int s0 = srcs[e], s1 = srcs[e + 1];
        float n0 = dinv[s0] * dvd;
        float n1 = dinv[s1] * dvd;
        size_t o0 = (size_t)s0 * D, o1 = (size_t)s1 * D;
        float v00 = x[o0 + lane], v01 = x[o0 + 64 + lane];
        float v10 = x[o1 + lane], v11 = x[o1 + 64 + lane];
        acc0 += v00 * n0;
        acc1 += v01 * n0;
        acc0 += v10 * n1;
        acc1 += v11 * n1;
    }
    if (e < end) {
        int s0 = srcs[e];
        float n0 = dinv[s0] * dvd;
        size_t o0 = (size_t)s0 * D;
        acc0 += x[o0 + lane] * n0;
        acc1 += x[o0 + 64 + lane] * n0;
    }
    agg[noff + lane] = acc0;
    agg[noff + 64 + lane] = acc1;
}

// ---------------- fused: out = x + relu(agg @ W^T + b) ----------
// (self-loop already folded into agg by gather_kernel)
__global__ __launch_bounds__(256) void final_kernel(const float* __restrict__ agg,
                                                    const float* __restrict__ x,
                                                    const float* __restrict__ W,
                                                    const float* __restrict__ bias,
                                                    float* __restrict__ out, int N) {
    __shared__ float Wl[128 * 132];     // 67.6 KB
    __shared__ float rowbuf[16 * 128];  // 8 KB
    const int lane = threadIdx.x & 63;
    const int wave = threadIdx.x >> 6;

    // stage W
    for (int idx = threadIdx.x; idx < 128 * 32; idx += 256) {
        int j = idx >> 5, c = idx & 31;
        float4 w = ((const float4*)W)[idx];
        *(float4*)&Wl[j * 132 + c * 4] = w;
    }

    // stage 16 rows of agg
    int base = blockIdx.x * 16;
    int trow = threadIdx.x >> 4;  // 0..15
    int tc = threadIdx.x & 15;    // float4 idx 0..15 (and +16)
    int grow = base + trow;
    if (grow < N) {
        size_t off = (size_t)grow * D;
        const float4* a4 = (const float4*)(agg + off);
        *(float4*)&rowbuf[trow * D + tc * 4] = a4[tc];
        *(float4*)&rowbuf[trow * D + (tc + 16) * 4] = a4[tc + 16];
    }
    __syncthreads();

    const int j0 = lane, j1 = lane + 64;
    float acc0[4] = {0.f, 0.f, 0.f, 0.f};
    float acc1[4] = {0.f, 0.f, 0.f, 0.f};
    const float* w0p = &Wl[j0 * 132];
    const float* w1p = &Wl[j1 * 132];
    const float* rp = &rowbuf[wave * 4 * D];
#pragma unroll 4
    for (int c = 0; c < 32; ++c) {
        float4 w0 = *(const float4*)(w0p + c * 4);
        float4 w1 = *(const float4*)(w1p + c * 4);
#pragma unroll
        for (int r = 0; r < 4; ++r) {
            float4 rv = *(const float4*)(rp + r * D + c * 4);
            acc0[r] += rv.x * w0.x + rv.y * w0.y + rv.z * w0.z + rv.w * w0.w;
            acc1[r] += rv.x * w1.x + rv.y * w1.y + rv.z * w1.z + rv.w * w1.w;
        }
    }

    float b0 = bias[j0], b1 = bias[j1];
#pragma unroll
    for (int r = 0; r < 4; ++r) {
        int row = base + wave * 4 + r;
        if (row < N) {
            size_t off = (size_t)row * D;
            float h0 = acc0[r] + b0;
            float h1 = acc1[r] + b1;
            out[off + j0] = x[off + j0] + (h0 > 0.f ? h0 : 0.f);
            out[off + j1] = x[off + j1] + (h1 > 0.f ? h1 : 0.f);
        }
    }
}

extern "C" void kernel_launch(void* const* d_in, const int* in_sizes, int n_in,
                              void* d_out, int out_size, void* d_ws, size_t ws_size,
                              hipStream_t stream) {
    const float* x = (const float*)d_in[0];
    const int* ei = (const int*)d_in[1];
    const float* W = (const float*)d_in[2];
    const float* bias = (const float*)d_in[3];
    float* out = (float*)d_out;

    const int N = in_sizes[0] / D;   // 50000
    const int E = in_sizes[1] / 2;   // 1,600,000
    const int* src = ei;
    const int* dst = ei + E;

    const int nb = (N + SCAN_B - 1) / SCAN_B;  // 196 scan blocks

    // workspace layout
    char* p = (char*)d_ws;
    float* agg = (float*)p;        p += (size_t)N * D * sizeof(float);   // 25.6 MB
    int* deg = (int*)p;            p += (size_t)N * sizeof(int);
    int* baseA = (int*)p;          p += (size_t)N * sizeof(int);
    float* dinv = (float*)p;       p += (size_t)N * sizeof(float);
    int* partials = (int*)p;       p += (size_t)nb * sizeof(int);
    int* srcs = (int*)p;           p += (size_t)E * sizeof(int);         // 6.4 MB

    // only deg needs zeroing (agg is fully written by gather)
    hipMemsetAsync(deg, 0, (size_t)N * sizeof(int), stream);

    deg_kernel<<<(E + 255) / 256, 256, 0, stream>>>(dst, deg, E);
    dinv_kernel<<<(N + 255) / 256, 256, 0, stream>>>(deg, dinv, N);

    scan_reduce<<<nb, SCAN_B, 0, stream>>>(deg, partials, N);
    scan_partials<<<1, 64, 0, stream>>>(partials, nb);
    scan_apply<<<nb, SCAN_B, 0, stream>>>(deg, partials, baseA, N);

    place_kernel<<<(E + 255) / 256, 256, 0, stream>>>(src, dst, baseA, srcs, E);

    gather_kernel<<<(N + 3) / 4, 256, 0, stream>>>(x, srcs, baseA, dinv, agg, N);

    final_kernel<<<(N + 15) / 16, 256, 0, stream>>>(agg, x, W, bias, out, N);
}

// Round 3
// 357.718 us; speedup vs baseline: 8.0442x; 1.2970x over previous
//
#include <hip/hip_runtime.h>

#define D 128
#define SCAN_B 256

// ---------------- fused degree + rank: rank[e] = deg[dst[e]]++ ----------------
__global__ __launch_bounds__(256) void rank_kernel(const int* __restrict__ dst,
                                                   int* __restrict__ deg,
                                                   int* __restrict__ rank, int E) {
    int e = blockIdx.x * 256 + threadIdx.x;
    if (e < E) rank[e] = atomicAdd(&deg[dst[e]], 1);
}

// ---------------- dinv = rsqrt(deg + 1 self-loop) ----------------
__global__ __launch_bounds__(256) void dinv_kernel(const int* __restrict__ deg,
                                                   float* __restrict__ dinv, int N) {
    int i = blockIdx.x * 256 + threadIdx.x;
    if (i < N) dinv[i] = rsqrtf((float)deg[i] + 1.0f);
}

// ---------------- scan step 1: per-block partial sums of deg ----------------
__global__ __launch_bounds__(SCAN_B) void scan_reduce(const int* __restrict__ deg,
                                                      int* __restrict__ partials, int N) {
    __shared__ int sh[SCAN_B];
    int t = threadIdx.x;
    int i = blockIdx.x * SCAN_B + t;
    sh[t] = (i < N) ? deg[i] : 0;
    __syncthreads();
    for (int off = SCAN_B / 2; off > 0; off >>= 1) {
        if (t < off) sh[t] += sh[t + off];
        __syncthreads();
    }
    if (t == 0) partials[blockIdx.x] = sh[0];
}

// ---------------- scan step 2: serial exclusive scan of partials; baseS[N]=E ----
__global__ void scan_partials(int* __restrict__ partials, int nb,
                              int* __restrict__ baseS, int N) {
    if (threadIdx.x == 0 && blockIdx.x == 0) {
        int run = 0;
        for (int i = 0; i < nb; ++i) {
            int t = partials[i];
            partials[i] = run;
            run += t;
        }
        baseS[N] = run;  // == E
    }
}

// ---------------- scan step 3: block-level exclusive scan + offset ----------------
__global__ __launch_bounds__(SCAN_B) void scan_apply(const int* __restrict__ deg,
                                                     const int* __restrict__ partials,
                                                     int* __restrict__ baseS, int N) {
    __shared__ int sh[SCAN_B];
    int t = threadIdx.x;
    int i = blockIdx.x * SCAN_B + t;
    int v = (i < N) ? deg[i] : 0;
    sh[t] = v;
    __syncthreads();
    for (int off = 1; off < SCAN_B; off <<= 1) {
        int add = (t >= off) ? sh[t - off] : 0;
        __syncthreads();
        sh[t] += add;
        __syncthreads();
    }
    if (i < N) baseS[i] = partials[blockIdx.x] + sh[t] - v;  // exclusive
}

// ---------------- placement: atomic-free counting sort by dst ----------------
__global__ __launch_bounds__(256) void place_kernel(const int* __restrict__ src,
                                                    const int* __restrict__ dst,
                                                    const int* __restrict__ rank,
                                                    const int* __restrict__ baseS,
                                                    int* __restrict__ srcs, int E) {
    int e = blockIdx.x * 256 + threadIdx.x;
    if (e < E) {
        srcs[baseS[dst[e]] + rank[e]] = src[e];
    }
}

// ---------------- gather: one wave per node, register accumulation ----------------
// lane l holds cols l and l+64. agg[d] = sum_e x[src_e]*dinv[src_e]*dinv[d] + x[d]*dinv[d]^2
__global__ __launch_bounds__(256) void gather_kernel(const float* __restrict__ x,
                                                     const int* __restrict__ srcs,
                                                     const int* __restrict__ baseS,
                                                     const float* __restrict__ dinv,
                                                     float* __restrict__ agg, int N) {
    int node = blockIdx.x * 4 + (threadIdx.x >> 6);
    if (node >= N) return;
    int lane = threadIdx.x & 63;
    int start = baseS[node];
    int end = baseS[node + 1];
    float dvd = dinv[node];
    size_t noff = (size_t)node * D;
    float acc0 = x[noff + lane] * dvd * dvd;  // self-loop
    float acc1 = x[noff + 64 + lane] * dvd * dvd;

    int e = start;
    for (; e + 3 < end; e += 4) {
        int s0 = srcs[e], s1 = srcs[e + 1], s2 = srcs[e + 2], s3 = srcs[e + 3];
        float n0 = dinv[s0] * dvd, n1 = dinv[s1] * dvd;
        float n2 = dinv[s2] * dvd, n3 = dinv[s3] * dvd;
        size_t o0 = (size_t)s0 * D, o1 = (size_t)s1 * D;
        size_t o2 = (size_t)s2 * D, o3 = (size_t)s3 * D;
        float a0 = x[o0 + lane], b0 = x[o0 + 64 + lane];
        float a1 = x[o1 + lane], b1 = x[o1 + 64 + lane];
        float a2 = x[o2 + lane], b2 = x[o2 + 64 + lane];
        float a3 = x[o3 + lane], b3 = x[o3 + 64 + lane];
        acc0 += a0 * n0 + a1 * n1 + a2 * n2 + a3 * n3;
        acc1 += b0 * n0 + b1 * n1 + b2 * n2 + b3 * n3;
    }
    for (; e < end; ++e) {
        int s0 = srcs[e];
        float n0 = dinv[s0] * dvd;
        size_t o0 = (size_t)s0 * D;
        acc0 += x[o0 + lane] * n0;
        acc1 += x[o0 + 64 + lane] * n0;
    }
    agg[noff + lane] = acc0;
    agg[noff + 64 + lane] = acc1;
}

// ---------------- fused: out = x + relu(agg @ W^T + b) ----------
__global__ __launch_bounds__(256) void final_kernel(const float* __restrict__ agg,
                                                    const float* __restrict__ x,
                                                    const float* __restrict__ W,
                                                    const float* __restrict__ bias,
                                                    float* __restrict__ out, int N) {
    __shared__ float Wl[128 * 132];     // 67.6 KB
    __shared__ float rowbuf[16 * 128];  // 8 KB
    const int lane = threadIdx.x & 63;
    const int wave = threadIdx.x >> 6;

    for (int idx = threadIdx.x; idx < 128 * 32; idx += 256) {
        int j = idx >> 5, c = idx & 31;
        float4 w = ((const float4*)W)[idx];
        *(float4*)&Wl[j * 132 + c * 4] = w;
    }

    int base = blockIdx.x * 16;
    int trow = threadIdx.x >> 4;
    int tc = threadIdx.x & 15;
    int grow = base + trow;
    if (grow < N) {
        size_t off = (size_t)grow * D;
        const float4* a4 = (const float4*)(agg + off);
        *(float4*)&rowbuf[trow * D + tc * 4] = a4[tc];
        *(float4*)&rowbuf[trow * D + (tc + 16) * 4] = a4[tc + 16];
    }
    __syncthreads();

    const int j0 = lane, j1 = lane + 64;
    float acc0[4] = {0.f, 0.f, 0.f, 0.f};
    float acc1[4] = {0.f, 0.f, 0.f, 0.f};
    const float* w0p = &Wl[j0 * 132];
    const float* w1p = &Wl[j1 * 132];
    const float* rp = &rowbuf[wave * 4 * D];
#pragma unroll 4
    for (int c = 0; c < 32; ++c) {
        float4 w0 = *(const float4*)(w0p + c * 4);
        float4 w1 = *(const float4*)(w1p + c * 4);
#pragma unroll
        for (int r = 0; r < 4; ++r) {
            float4 rv = *(const float4*)(rp + r * D + c * 4);
            acc0[r] += rv.x * w0.x + rv.y * w0.y + rv.z * w0.z + rv.w * w0.w;
            acc1[r] += rv.x * w1.x + rv.y * w1.y + rv.z * w1.z + rv.w * w1.w;
        }
    }

    float b0 = bias[j0], b1 = bias[j1];
#pragma unroll
    for (int r = 0; r < 4; ++r) {
        int row = base + wave * 4 + r;
        if (row < N) {
            size_t off = (size_t)row * D;
            float h0 = acc0[r] + b0;
            float h1 = acc1[r] + b1;
            out[off + j0] = x[off + j0] + (h0 > 0.f ? h0 : 0.f);
            out[off + j1] = x[off + j1] + (h1 > 0.f ? h1 : 0.f);
        }
    }
}

extern "C" void kernel_launch(void* const* d_in, const int* in_sizes, int n_in,
                              void* d_out, int out_size, void* d_ws, size_t ws_size,
                              hipStream_t stream) {
    const float* x = (const float*)d_in[0];
    const int* ei = (const int*)d_in[1];
    const float* W = (const float*)d_in[2];
    const float* bias = (const float*)d_in[3];
    float* out = (float*)d_out;

    const int N = in_sizes[0] / D;   // 50000
    const int E = in_sizes[1] / 2;   // 1,600,000
    const int* src = ei;
    const int* dst = ei + E;

    const int nb = (N + SCAN_B - 1) / SCAN_B;

    // workspace layout
    char* p = (char*)d_ws;
    float* agg = (float*)p;   p += (size_t)N * D * sizeof(float);    // 25.6 MB
    int* deg = (int*)p;       p += (size_t)N * sizeof(int);
    int* baseS = (int*)p;     p += (size_t)(N + 1) * sizeof(int);
    float* dinv = (float*)p;  p += (size_t)N * sizeof(float);
    int* partials = (int*)p;  p += (size_t)nb * sizeof(int);
    int* rank = (int*)p;      p += (size_t)E * sizeof(int);          // 6.4 MB
    int* srcs = (int*)p;      p += (size_t)E * sizeof(int);          // 6.4 MB

    hipMemsetAsync(deg, 0, (size_t)N * sizeof(int), stream);

    rank_kernel<<<(E + 255) / 256, 256, 0, stream>>>(dst, deg, rank, E);
    dinv_kernel<<<(N + 255) / 256, 256, 0, stream>>>(deg, dinv, N);

    scan_reduce<<<nb, SCAN_B, 0, stream>>>(deg, partials, N);
    scan_partials<<<1, 64, 0, stream>>>(partials, nb, baseS, N);
    scan_apply<<<nb, SCAN_B, 0, stream>>>(deg, partials, baseS, N);

    place_kernel<<<(E + 255) / 256, 256, 0, stream>>>(src, dst, rank, baseS, srcs, E);

    gather_kernel<<<(N + 3) / 4, 256, 0, stream>>>(x, srcs, baseS, dinv, agg, N);

    final_kernel<<<(N + 15) / 16, 256, 0, stream>>>(agg, x, W, bias, out, N);
}

// Round 4
// 335.670 us; speedup vs baseline: 8.5726x; 1.0657x over previous
//
#include <hip/hip_runtime.h>
#include <hip/hip_fp16.h>

#define D 128
#define SCAN_B 256

// ---------------- fused degree + rank: rank[e] = deg[dst[e]]++ ----------------
__global__ __launch_bounds__(256) void rank_kernel(const int* __restrict__ dst,
                                                   int* __restrict__ deg,
                                                   int* __restrict__ rank, int E) {
    int e = blockIdx.x * 256 + threadIdx.x;
    if (e < E) rank[e] = atomicAdd(&deg[dst[e]], 1);
}

// ---------------- scan step 1: per-block partial sums of deg ----------------
__global__ __launch_bounds__(SCAN_B) void scan_reduce(const int* __restrict__ deg,
                                                      int* __restrict__ partials, int N) {
    __shared__ int sh[SCAN_B];
    int t = threadIdx.x;
    int i = blockIdx.x * SCAN_B + t;
    sh[t] = (i < N) ? deg[i] : 0;
    __syncthreads();
    for (int off = SCAN_B / 2; off > 0; off >>= 1) {
        if (t < off) sh[t] += sh[t + off];
        __syncthreads();
    }
    if (t == 0) partials[blockIdx.x] = sh[0];
}

// ---------------- scan step 2: serial exclusive scan of partials; baseS[N]=E ----
__global__ void scan_partials(int* __restrict__ partials, int nb,
                              int* __restrict__ baseS, int N) {
    if (threadIdx.x == 0 && blockIdx.x == 0) {
        int run = 0;
        for (int i = 0; i < nb; ++i) {
            int t = partials[i];
            partials[i] = run;
            run += t;
        }
        baseS[N] = run;  // == E
    }
}

// ---------------- scan step 3: block-level exclusive scan + offset ----------------
__global__ __launch_bounds__(SCAN_B) void scan_apply(const int* __restrict__ deg,
                                                     const int* __restrict__ partials,
                                                     int* __restrict__ baseS, int N) {
    __shared__ int sh[SCAN_B];
    int t = threadIdx.x;
    int i = blockIdx.x * SCAN_B + t;
    int v = (i < N) ? deg[i] : 0;
    sh[t] = v;
    __syncthreads();
    for (int off = 1; off < SCAN_B; off <<= 1) {
        int add = (t >= off) ? sh[t - off] : 0;
        __syncthreads();
        sh[t] += add;
        __syncthreads();
    }
    if (i < N) baseS[i] = partials[blockIdx.x] + sh[t] - v;  // exclusive
}

// ---------------- placement: atomic-free counting sort by dst ----------------
__global__ __launch_bounds__(256) void place_kernel(const int* __restrict__ src,
                                                    const int* __restrict__ dst,
                                                    const int* __restrict__ rank,
                                                    const int* __restrict__ baseS,
                                                    int* __restrict__ srcs, int E) {
    int e = blockIdx.x * 256 + threadIdx.x;
    if (e < E) {
        srcs[baseS[dst[e]] + rank[e]] = src[e];
    }
}

// ---------------- dinv + pre-scaled fp16 x: xs[s] = fp16(x[s] * dinv[s]) ------
// One wave per node; lane l handles cols 2l, 2l+1.
__global__ __launch_bounds__(256) void dinv_xs_kernel(const float* __restrict__ x,
                                                      const int* __restrict__ deg,
                                                      float* __restrict__ dinv,
                                                      __half* __restrict__ xs, int N) {
    int node = blockIdx.x * 4 + (threadIdx.x >> 6);
    if (node >= N) return;
    int lane = threadIdx.x & 63;
    float dv = rsqrtf((float)deg[node] + 1.0f);
    if (lane == 0) dinv[node] = dv;
    size_t noff = (size_t)node * D;
    float2 v = ((const float2*)(x + noff))[lane];
    ((__half2*)(xs + noff))[lane] = __floats2half2_rn(v.x * dv, v.y * dv);
}

// ---------------- gather: one wave per node, fp16 packed rows ----------------
// agg[d] = dinv[d] * sum_e xs[src_e] + x[d]*dinv[d]^2 ; lane l -> cols 2l,2l+1
__global__ __launch_bounds__(256) void gather_kernel(const float* __restrict__ x,
                                                     const __half* __restrict__ xs,
                                                     const int* __restrict__ srcs,
                                                     const int* __restrict__ baseS,
                                                     const float* __restrict__ dinv,
                                                     float* __restrict__ agg, int N) {
    int node = blockIdx.x * 4 + (threadIdx.x >> 6);
    if (node >= N) return;
    int lane = threadIdx.x & 63;
    int start = baseS[node];
    int end = baseS[node + 1];
    float dvd = dinv[node];
    size_t noff = (size_t)node * D;
    const __half2* xs2 = (const __half2*)xs;  // row s at s*64 + lane

    float2 xv = ((const float2*)(x + noff))[lane];
    float s0 = 0.f, s1 = 0.f;

    int e = start;
    for (; e + 7 < end; e += 8) {
        int i0 = srcs[e + 0], i1 = srcs[e + 1], i2 = srcs[e + 2], i3 = srcs[e + 3];
        int i4 = srcs[e + 4], i5 = srcs[e + 5], i6 = srcs[e + 6], i7 = srcs[e + 7];
        float2 f0 = __half22float2(xs2[(size_t)i0 * 64 + lane]);
        float2 f1 = __half22float2(xs2[(size_t)i1 * 64 + lane]);
        float2 f2 = __half22float2(xs2[(size_t)i2 * 64 + lane]);
        float2 f3 = __half22float2(xs2[(size_t)i3 * 64 + lane]);
        float2 f4 = __half22float2(xs2[(size_t)i4 * 64 + lane]);
        float2 f5 = __half22float2(xs2[(size_t)i5 * 64 + lane]);
        float2 f6 = __half22float2(xs2[(size_t)i6 * 64 + lane]);
        float2 f7 = __half22float2(xs2[(size_t)i7 * 64 + lane]);
        s0 += (f0.x + f1.x) + (f2.x + f3.x) + ((f4.x + f5.x) + (f6.x + f7.x));
        s1 += (f0.y + f1.y) + (f2.y + f3.y) + ((f4.y + f5.y) + (f6.y + f7.y));
    }
    for (; e < end; ++e) {
        float2 f = __half22float2(xs2[(size_t)srcs[e] * 64 + lane]);
        s0 += f.x;
        s1 += f.y;
    }

    float acc0 = xv.x * dvd * dvd + s0 * dvd;
    float acc1 = xv.y * dvd * dvd + s1 * dvd;
    ((float2*)(agg + noff))[lane] = make_float2(acc0, acc1);
}

// ---------------- fused: out = x + relu(agg @ W^T + b) ----------
__global__ __launch_bounds__(256) void final_kernel(const float* __restrict__ agg,
                                                    const float* __restrict__ x,
                                                    const float* __restrict__ W,
                                                    const float* __restrict__ bias,
                                                    float* __restrict__ out, int N) {
    __shared__ float Wl[128 * 132];     // 67.6 KB
    __shared__ float rowbuf[16 * 128];  // 8 KB
    const int lane = threadIdx.x & 63;
    const int wave = threadIdx.x >> 6;

    for (int idx = threadIdx.x; idx < 128 * 32; idx += 256) {
        int j = idx >> 5, c = idx & 31;
        float4 w = ((const float4*)W)[idx];
        *(float4*)&Wl[j * 132 + c * 4] = w;
    }

    int base = blockIdx.x * 16;
    int trow = threadIdx.x >> 4;
    int tc = threadIdx.x & 15;
    int grow = base + trow;
    if (grow < N) {
        size_t off = (size_t)grow * D;
        const float4* a4 = (const float4*)(agg + off);
        *(float4*)&rowbuf[trow * D + tc * 4] = a4[tc];
        *(float4*)&rowbuf[trow * D + (tc + 16) * 4] = a4[tc + 16];
    }
    __syncthreads();

    const int j0 = lane, j1 = lane + 64;
    float acc0[4] = {0.f, 0.f, 0.f, 0.f};
    float acc1[4] = {0.f, 0.f, 0.f, 0.f};
    const float* w0p = &Wl[j0 * 132];
    const float* w1p = &Wl[j1 * 132];
    const float* rp = &rowbuf[wave * 4 * D];
#pragma unroll 4
    for (int c = 0; c < 32; ++c) {
        float4 w0 = *(const float4*)(w0p + c * 4);
        float4 w1 = *(const float4*)(w1p + c * 4);
#pragma unroll
        for (int r = 0; r < 4; ++r) {
            float4 rv = *(const float4*)(rp + r * D + c * 4);
            acc0[r] += rv.x * w0.x + rv.y * w0.y + rv.z * w0.z + rv.w * w0.w;
            acc1[r] += rv.x * w1.x + rv.y * w1.y + rv.z * w1.z + rv.w * w1.w;
        }
    }

    float b0 = bias[j0], b1 = bias[j1];
#pragma unroll
    for (int r = 0; r < 4; ++r) {
        int row = base + wave * 4 + r;
        if (row < N) {
            size_t off = (size_t)row * D;
            float h0 = acc0[r] + b0;
            float h1 = acc1[r] + b1;
            out[off + j0] = x[off + j0] + (h0 > 0.f ? h0 : 0.f);
            out[off + j1] = x[off + j1] + (h1 > 0.f ? h1 : 0.f);
        }
    }
}

extern "C" void kernel_launch(void* const* d_in, const int* in_sizes, int n_in,
                              void* d_out, int out_size, void* d_ws, size_t ws_size,
                              hipStream_t stream) {
    const float* x = (const float*)d_in[0];
    const int* ei = (const int*)d_in[1];
    const float* W = (const float*)d_in[2];
    const float* bias = (const float*)d_in[3];
    float* out = (float*)d_out;

    const int N = in_sizes[0] / D;   // 50000
    const int E = in_sizes[1] / 2;   // 1,600,000
    const int* src = ei;
    const int* dst = ei + E;

    const int nb = (N + SCAN_B - 1) / SCAN_B;

    // workspace layout. NOTE: xs (fp16, N*D = 12.8 MB) OVERLAYS rank (6.4 MB)
    // plus 6.4 MB beyond — rank is dead after place_kernel, and dinv_xs_kernel
    // (which writes xs) runs after place_kernel.
    char* p = (char*)d_ws;
    float* agg = (float*)p;   p += (size_t)N * D * sizeof(float);    // 25.6 MB
    int* deg = (int*)p;       p += (size_t)N * sizeof(int);
    int* baseS = (int*)p;     p += (size_t)(N + 1) * sizeof(int);
    float* dinv = (float*)p;  p += (size_t)N * sizeof(float);
    int* partials = (int*)p;  p += (size_t)nb * sizeof(int);
    int* srcs = (int*)p;      p += (size_t)E * sizeof(int);          // 6.4 MB
    int* rank = (int*)p;      // 6.4 MB, dead after place
    __half* xs = (__half*)p;  // 12.8 MB, overlays rank (+6.4 MB beyond)

    hipMemsetAsync(deg, 0, (size_t)N * sizeof(int), stream);

    rank_kernel<<<(E + 255) / 256, 256, 0, stream>>>(dst, deg, rank, E);

    scan_reduce<<<nb, SCAN_B, 0, stream>>>(deg, partials, N);
    scan_partials<<<1, 64, 0, stream>>>(partials, nb, baseS, N);
    scan_apply<<<nb, SCAN_B, 0, stream>>>(deg, partials, baseS, N);

    place_kernel<<<(E + 255) / 256, 256, 0, stream>>>(src, dst, rank, baseS, srcs, E);

    dinv_xs_kernel<<<(N + 3) / 4, 256, 0, stream>>>(x, deg, dinv, xs, N);

    gather_kernel<<<(N + 3) / 4, 256, 0, stream>>>(x, xs, srcs, baseS, dinv, agg, N);

    final_kernel<<<(N + 15) / 16, 256, 0, stream>>>(agg, x, W, bias, out, N);
}